// Round 1
// baseline (247.744 us; speedup 1.0000x reference)
//
#include <hip/hip_runtime.h>

#define T_ROWS 16
#define NROWS  65536
#define CDIM   128
#define MKEYS  1024

typedef _Float16 half8 __attribute__((ext_vector_type(8)));
typedef _Float16 half4 __attribute__((ext_vector_type(4)));
typedef float    floatx4 __attribute__((ext_vector_type(4)));

union FU { float f; unsigned u; };

// ---------------- Kernel A: convert keys fp32 -> fp16 (row-major [1024][128]) --------
__global__ __launch_bounds__(256) void cvt_keys_kernel(const float* __restrict__ keys,
                                                       _Float16* __restrict__ kh) {
    int i = blockIdx.x * 256 + threadIdx.x;          // 32768 threads, 4 elems each
    float4 f = ((const float4*)keys)[i];
    half4 hv;
    hv[0] = (_Float16)f.x; hv[1] = (_Float16)f.y;
    hv[2] = (_Float16)f.z; hv[3] = (_Float16)f.w;
    ((half4*)kh)[i] = hv;
}

// ---------------- Kernel B: fused score/argmax/rescue/gather ------------------------
__global__ __launch_bounds__(256) void gather_main(
    const float* __restrict__ q,      // trend_representation (65536x128)
    const float* __restrict__ rep,    // representation
    const float* __restrict__ keys,   // fp32 keys (1024x128)
    const float* __restrict__ vals,   // fp32 values
    const _Float16* __restrict__ kh,  // fp16 keys (ws)
    float* __restrict__ out)          // [131072]: keys_g then values_g
{
    __shared__ unsigned short sc[T_ROWS][1024];   // bf16-truncated scores, swizzled (32 KB)
    __shared__ _Float16 qh[T_ROWS][128];          // fp16 q, swizzled (4 KB)
    __shared__ float qss[256];
    __shared__ float wm1[4][T_ROWS];
    __shared__ int   wi1[4][T_ROWS];
    __shared__ float rowT[T_ROWS];
    __shared__ int   rowI1s[T_ROWS];
    __shared__ int   candCnt[T_ROWS];
    __shared__ int   candKey[T_ROWS][16];
    __shared__ int   rowOvf[T_ROWS];
    __shared__ unsigned long long rowBest[T_ROWS];
    __shared__ int   rowIdx[T_ROWS];
    __shared__ float kgp[256], vgp[256];

    const int t    = threadIdx.x;
    const int wid  = t >> 6;
    const int lane = t & 63;
    const int n    = lane & 15;       // A: key-in-16, B: row-in-16, C: col=row
    const int quad = lane >> 4;       // k-chunk selector / C row group
    const long g0  = (long)blockIdx.x * T_ROWS;

    if (t < T_ROWS) { candCnt[t] = 0; rowOvf[t] = 0; rowBest[t] = 0ull; }

    // ---- P1: stage q tile -> fp16 LDS (swizzled), accumulate per-row sumsq ----
    {
        int row = t >> 4, c8 = t & 15;
        const float4* src = (const float4*)(q + (g0 + row) * CDIM + c8 * 8);
        float4 a0 = src[0], a1 = src[1];
        qss[t] = a0.x*a0.x + a0.y*a0.y + a0.z*a0.z + a0.w*a0.w
               + a1.x*a1.x + a1.y*a1.y + a1.z*a1.z + a1.w*a1.w;
        half8 hv;
        hv[0] = (_Float16)a0.x; hv[1] = (_Float16)a0.y;
        hv[2] = (_Float16)a0.z; hv[3] = (_Float16)a0.w;
        hv[4] = (_Float16)a1.x; hv[5] = (_Float16)a1.y;
        hv[6] = (_Float16)a1.z; hv[7] = (_Float16)a1.w;
        int phys = c8 ^ (row & 7);
        *(half8*)&qh[row][phys * 8] = hv;
    }
    __syncthreads();

    // ---- P2: hoist B-fragments (q) into registers; no LDS reads in K-loop ----
    half8 qf0, qf1, qf2, qf3;
    {
        int p0 = (0 * 4 + quad) ^ (n & 7);
        int p1 = (1 * 4 + quad) ^ (n & 7);
        int p2 = (2 * 4 + quad) ^ (n & 7);
        int p3 = (3 * 4 + quad) ^ (n & 7);
        qf0 = *(const half8*)&qh[n][p0 * 8];
        qf1 = *(const half8*)&qh[n][p1 * 8];
        qf2 = *(const half8*)&qh[n][p2 * 8];
        qf3 = *(const half8*)&qh[n][p3 * 8];
    }

    // ---- P3: 16 chunks x 64 keys; MFMA + running max + bf16 score store ----
    float m1 = -3.4e38f; int i1 = 0;
    for (int ch = 0; ch < 16; ++ch) {
        int kb = ch * 64 + wid * 16;
        const _Float16* kp = kh + (long)(kb + n) * CDIM + quad * 8;
        half8 a0 = *(const half8*)(kp + 0);
        half8 a1 = *(const half8*)(kp + 32);
        half8 a2 = *(const half8*)(kp + 64);
        half8 a3 = *(const half8*)(kp + 96);
        floatx4 acc = {0.f, 0.f, 0.f, 0.f};
        acc = __builtin_amdgcn_mfma_f32_16x16x32_f16(a0, qf0, acc, 0, 0, 0);
        acc = __builtin_amdgcn_mfma_f32_16x16x32_f16(a1, qf1, acc, 0, 0, 0);
        acc = __builtin_amdgcn_mfma_f32_16x16x32_f16(a2, qf2, acc, 0, 0, 0);
        acc = __builtin_amdgcn_mfma_f32_16x16x32_f16(a3, qf3, acc, 0, 0, 0);
        int keyb = kb + quad * 4;     // C layout: m = quad*4 + reg
        float s0 = acc[0], s1 = acc[1], s2 = acc[2], s3 = acc[3];
        if (s0 > m1) { m1 = s0; i1 = keyb;     }
        if (s1 > m1) { m1 = s1; i1 = keyb + 1; }
        if (s2 > m1) { m1 = s2; i1 = keyb + 2; }
        if (s3 > m1) { m1 = s3; i1 = keyb + 3; }
        FU u0, u1, u2, u3; u0.f = s0; u1.f = s1; u2.f = s2; u3.f = s3;
        unsigned lo = (u0.u >> 16) | (u1.u & 0xffff0000u);
        unsigned hi = (u2.u >> 16) | (u3.u & 0xffff0000u);
        int phys = ((kb >> 3) + (quad >> 1)) ^ (n & 7);
        unsigned* p = (unsigned*)&sc[n][phys * 8 + (quad & 1) * 4];
        p[0] = lo; p[1] = hi;
    }

    // ---- P4: merge running max across quads (same row, disjoint keys) ----
    {
        float om; int oi; bool take;
        om = __shfl_xor(m1, 16); oi = __shfl_xor(i1, 16);
        take = (om > m1) || (om == m1 && oi < i1);
        if (take) { m1 = om; i1 = oi; }
        om = __shfl_xor(m1, 32); oi = __shfl_xor(i1, 32);
        take = (om > m1) || (om == m1 && oi < i1);
        if (take) { m1 = om; i1 = oi; }
    }
    if (lane < 16) { wm1[wid][lane] = m1; wi1[wid][lane] = i1; }
    __syncthreads();

    // ---- P5: merge across waves; compute rigorous candidate threshold ----
    if (t < T_ROWS) {
        float M1 = wm1[0][t]; int I1 = wi1[0][t];
        for (int w = 1; w < 4; ++w) {
            float om = wm1[w][t]; int oi = wi1[w][t];
            if (om > M1 || (om == M1 && oi < I1)) { M1 = om; I1 = oi; }
        }
        float qn2 = 0.f;
        for (int j = 0; j < 16; ++j) qn2 += qss[t * 16 + j];
        float qn = sqrtf(qn2);
        // fp16 rounding: |s~ - s| <= 2^-10*1.01*||q||*||k||max(<=17) + fp32-acc slack
        float e1 = 0.0168f * qn + 0.002f;
        // + bf16 truncation of stored scores (<= 2^-8 |s|)
        rowT[t]  = M1 - (2.f * e1 + 0.0040f * fabsf(M1) + 0.02f);
        rowI1s[t] = I1;
    }
    __syncthreads();

    // ---- P6: scan cached scores, collect candidates >= threshold ----
    {
        int row = t >> 4, seg = t & 15;
        float Tthr = rowT[row];
        for (int i = 0; i < 8; ++i) {
            int kk = seg * 8 + i;
            int phys = kk ^ (row & 7);
            uint4 d = *(const uint4*)&sc[row][phys * 8];
            unsigned dw[4] = {d.x, d.y, d.z, d.w};
            #pragma unroll
            for (int j = 0; j < 4; ++j) {
                FU fe, fo;
                fe.u = dw[j] << 16;
                fo.u = dw[j] & 0xffff0000u;
                int kbase = kk * 8 + j * 2;
                if (fe.f >= Tthr) {
                    int pos = atomicAdd(&candCnt[row], 1);
                    if (pos < 16) candKey[row][pos] = kbase; else rowOvf[row] = 1;
                }
                if (fo.f >= Tthr) {
                    int pos = atomicAdd(&candCnt[row], 1);
                    if (pos < 16) candKey[row][pos] = kbase + 1; else rowOvf[row] = 1;
                }
            }
        }
    }
    __syncthreads();

    // ---- P7: exact fp32 rescoring of candidates; atomicMax packed (score,1023-key) ----
    {
        int row = t >> 4, slot = t & 15;
        int cnt = candCnt[row];
        if (!rowOvf[row] && slot < cnt) {
            int key = candKey[row][slot];
            const float* qp = q + (g0 + row) * CDIM;
            const float* kp = keys + (long)key * CDIM;
            float acc0 = 0.f, acc1 = 0.f;
            for (int c = 0; c < CDIM; c += 8) {
                float4 qa = *(const float4*)(qp + c);
                float4 ka = *(const float4*)(kp + c);
                float4 qb = *(const float4*)(qp + c + 4);
                float4 kb4 = *(const float4*)(kp + c + 4);
                acc0 += qa.x*ka.x + qa.y*ka.y + qa.z*ka.z + qa.w*ka.w;
                acc1 += qb.x*kb4.x + qb.y*kb4.y + qb.z*kb4.z + qb.w*kb4.w;
            }
            FU su; su.f = acc0 + acc1;
            unsigned ord = (su.u & 0x80000000u) ? ~su.u : (su.u | 0x80000000u);
            unsigned long long enc = ((unsigned long long)ord << 32) | (unsigned)(1023 - key);
            atomicMax(&rowBest[row], enc);
        }
        // overflow fallback: exact rescan of all 1024 keys (rigor path, ~never taken)
        for (int rr = 0; rr < T_ROWS; ++rr) {
            if (rowOvf[rr]) {
                const float* qp = q + (g0 + rr) * CDIM;
                for (int kkk = 0; kkk < 4; ++kkk) {
                    int key = t * 4 + kkk;
                    const float* kp = keys + (long)key * CDIM;
                    float acc0 = 0.f, acc1 = 0.f;
                    for (int c = 0; c < CDIM; c += 8) {
                        float4 qa = *(const float4*)(qp + c);
                        float4 ka = *(const float4*)(kp + c);
                        float4 qb = *(const float4*)(qp + c + 4);
                        float4 kb4 = *(const float4*)(kp + c + 4);
                        acc0 += qa.x*ka.x + qa.y*ka.y + qa.z*ka.z + qa.w*ka.w;
                        acc1 += qb.x*kb4.x + qb.y*kb4.y + qb.z*kb4.z + qb.w*kb4.w;
                    }
                    FU su; su.f = acc0 + acc1;
                    unsigned ord = (su.u & 0x80000000u) ? ~su.u : (su.u | 0x80000000u);
                    unsigned long long enc = ((unsigned long long)ord << 32) | (unsigned)(1023 - key);
                    atomicMax(&rowBest[rr], enc);
                }
            }
        }
    }
    __syncthreads();

    // ---- P8: decode winning index ----
    if (t < T_ROWS) {
        unsigned long long b = rowBest[t];
        rowIdx[t] = b ? (1023 - (int)(unsigned)(b & 0xffffffffull)) : rowI1s[t];
    }
    __syncthreads();

    // ---- P9: fused gather: sum (q-k)^2 and (r-v)^2 in fp32 ----
    {
        int row = t >> 4, c8 = t & 15;
        int idx = rowIdx[row];
        long g = g0 + row;
        const float4* qp = (const float4*)(q    + g * CDIM + c8 * 8);
        const float4* kp = (const float4*)(keys + (long)idx * CDIM + c8 * 8);
        const float4* rp = (const float4*)(rep  + g * CDIM + c8 * 8);
        const float4* vp = (const float4*)(vals + (long)idx * CDIM + c8 * 8);
        float kg = 0.f, vg = 0.f;
        #pragma unroll
        for (int h = 0; h < 2; ++h) {
            float4 qa = qp[h], ka = kp[h], ra = rp[h], va = vp[h];
            float d0 = qa.x - ka.x, d1 = qa.y - ka.y, d2 = qa.z - ka.z, d3 = qa.w - ka.w;
            kg += d0*d0 + d1*d1 + d2*d2 + d3*d3;
            float e0 = ra.x - va.x, e1 = ra.y - va.y, e2 = ra.z - va.z, e3 = ra.w - va.w;
            vg += e0*e0 + e1*e1 + e2*e2 + e3*e3;
        }
        kgp[t] = kg; vgp[t] = vg;
    }
    __syncthreads();
    if (t < T_ROWS) {
        float a = 0.f, b = 0.f;
        for (int j = 0; j < 16; ++j) { a += kgp[t * 16 + j]; b += vgp[t * 16 + j]; }
        long g = g0 + t;
        out[g] = a;
        out[NROWS + g] = b;
    }
}

extern "C" void kernel_launch(void* const* d_in, const int* in_sizes, int n_in,
                              void* d_out, int out_size, void* d_ws, size_t ws_size,
                              hipStream_t stream) {
    const float* q    = (const float*)d_in[0];  // trend_representation
    const float* rep  = (const float*)d_in[1];  // representation
    const float* keys = (const float*)d_in[2];
    const float* vals = (const float*)d_in[3];
    _Float16* kh = (_Float16*)d_ws;             // 256 KB fp16 key cache

    cvt_keys_kernel<<<128, 256, 0, stream>>>(keys, kh);
    gather_main<<<NROWS / T_ROWS, 256, 0, stream>>>(q, rep, keys, vals, kh,
                                                    (float*)d_out);
}